// Round 10
// baseline (1873.393 us; speedup 1.0000x reference)
//
#include <hip/hip_runtime.h>
#include <hip/hip_bf16.h>
#include <math.h>

// Problem constants
#define NN 200
#define FF 8
#define TT 12
#define OO 32
#define DD 19200          // N*F*T
#define EE 1600
#define D4 4800           // DD/4

typedef float f32x4 __attribute__((ext_vector_type(4)));

// ---------------- Kernel 1: xf = x_flat @ W_mlp.T  (GEMV, HBM-bound) -------
// One wave (64 lanes) per output row. Row i of W_mlp is contiguous (19200 f32).
// W is streamed once -> nontemporal loads; x (76.8KB) stays hot in cache.
__global__ __launch_bounds__(256) void gemv_kernel(
    const float* __restrict__ x, const float* __restrict__ W,
    float* __restrict__ xf)
{
    const int wave = threadIdx.x >> 6;          // 0..3
    const int lane = threadIdx.x & 63;
    const int row  = blockIdx.x * 4 + wave;     // 0..19199
    const f32x4* __restrict__ wrow = (const f32x4*)(W + (size_t)row * DD);
    const f32x4* __restrict__ x4   = (const f32x4*)x;

    float acc = 0.f;
    #pragma unroll
    for (int k = 0; k < 75; ++k) {
        const int v = lane + (k << 6);          // lane + k*64, < 4800
        const f32x4 wv = __builtin_nontemporal_load(&wrow[v]);
        const f32x4 xv = x4[v];
        acc += wv.x * xv.x + wv.y * xv.y + wv.z * xv.z + wv.w * xv.w;
    }
    // wave64 reduction
    #pragma unroll
    for (int off = 32; off > 0; off >>= 1)
        acc += __shfl_down(acc, off);
    if (lane == 0) xf[row] = acc;
}

// ---------------- Kernel 2: fused {gcn_norm + softmax(att)} | xw einsum ----
// Block 0: prep (degree, norms, softmax). Blocks 1..NN: per-node xw.
// xw[n,t,o] = sum_f xf[n*96 + f*12 + t] * W[f,o]
__global__ __launch_bounds__(384) void xw_prep_kernel(
    const float* __restrict__ xf,
    const float* __restrict__ Wz, const float* __restrict__ Wh,
    const int* __restrict__ ei, const float* __restrict__ ew,
    const float* __restrict__ att,
    float* __restrict__ xwz, float* __restrict__ xwh,
    float* __restrict__ norm, float* __restrict__ normself,
    float* __restrict__ probs)
{
    const int tid = threadIdx.x;
    if (blockIdx.x == 0) {
        // ---- prep path (independent of xf) ----
        __shared__ float degL[NN];
        __shared__ float dinvL[NN];
        if (tid < NN) degL[tid] = 0.f;
        __syncthreads();
        for (int e = tid; e < EE; e += 384)
            atomicAdd(&degL[ei[EE + e]], ew[e]);       // deg over dst
        __syncthreads();
        if (tid < NN) {
            const float d = degL[tid] + 1.0f;          // + self-loop weight 1
            dinvL[tid] = 1.0f / sqrtf(d);              // d >= 1 always
        }
        __syncthreads();
        for (int e = tid; e < EE; e += 384) {
            const int s = ei[e], dn = ei[EE + e];
            norm[e] = dinvL[s] * ew[e] * dinvL[dn];
        }
        if (tid < NN) normself[tid] = dinvL[tid] * dinvL[tid];
        if (tid == 0) {
            float a[TT], m = -1e30f, ssum = 0.f;
            for (int t = 0; t < TT; ++t) { a[t] = att[t]; m = fmaxf(m, a[t]); }
            for (int t = 0; t < TT; ++t) { a[t] = expf(a[t] - m); ssum += a[t]; }
            for (int t = 0; t < TT; ++t) probs[t] = a[t] / ssum;
        }
        return;
    }
    // ---- xw path ----
    const int n = blockIdx.x - 1;
    __shared__ float xs[FF * TT];                      // 96
    if (tid < FF * TT) xs[tid] = xf[n * (FF * TT) + tid];
    __syncthreads();
    const int t = tid >> 5, o = tid & 31;
    float az = 0.f, ah = 0.f;
    #pragma unroll
    for (int f = 0; f < FF; ++f) {
        const float xv = xs[f * TT + t];
        az += xv * Wz[f * OO + o];
        ah += xv * Wh[f * OO + o];
    }
    xwz[n * 384 + tid] = az;
    xwh[n * 384 + tid] = ah;
}

// ---------------- Kernel 3: aggregate + GRU gates + attention + out --------
// 200 blocks (one per dst node), 384 threads = (t,o) then (t,p).
__global__ __launch_bounds__(384) void final_kernel(
    const int* __restrict__ ei,
    const float* __restrict__ norm, const float* __restrict__ normself,
    const float* __restrict__ xwz, const float* __restrict__ xwh,
    const float* __restrict__ bz, const float* __restrict__ bh,
    const float* __restrict__ Lz, const float* __restrict__ blz,
    const float* __restrict__ Lh, const float* __restrict__ blh,
    const float* __restrict__ probs,
    const float* __restrict__ Wout, const float* __restrict__ bout,
    float* __restrict__ out)
{
    const int n = blockIdx.x, tid = threadIdx.x;
    __shared__ int matchE[400];
    __shared__ int matchS[400];
    __shared__ int mcount;
    __shared__ float CzL[384], ChL[384], HpL[384], HL[OO], probsL[TT];

    if (tid == 0) mcount = 0;
    if (tid < TT) probsL[tid] = probs[tid];
    __syncthreads();

    // collect incoming edges of node n (expected in-degree ~8, max ~25)
    for (int e = tid; e < EE; e += 384) {
        if (ei[EE + e] == n) {
            const int slot = atomicAdd(&mcount, 1);
            matchE[slot] = e;
            matchS[slot] = ei[e];
        }
    }
    __syncthreads();

    // message aggregation for this (t,o)
    float az = normself[n] * xwz[n * 384 + tid];
    float ah = normself[n] * xwh[n * 384 + tid];
    const int mc = mcount;
    for (int i = 0; i < mc; ++i) {
        const int e = matchE[i], s = matchS[i];
        const float nm = norm[e];
        az += nm * xwz[s * 384 + tid];
        ah += nm * xwh[s * 384 + tid];
    }
    const int o = tid & 31;
    CzL[tid] = az + bz[o];
    ChL[tid] = ah + bh[o];
    __syncthreads();

    // gates: thread = (t,p);  Z = sigmoid(Cz @ Lz[:, :O].T + blz) etc.
    const int t = tid >> 5, p = tid & 31;
    float sz = blz[p], sh = blh[p];
    #pragma unroll
    for (int oo = 0; oo < OO; ++oo) {
        sz += CzL[t * OO + oo] * Lz[p * (2 * OO) + oo];
        sh += ChL[t * OO + oo] * Lh[p * (2 * OO) + oo];
    }
    const float Zv  = 1.f / (1.f + expf(-sz));
    const float Htv = tanhf(sh);
    HpL[tid] = (1.f - Zv) * Htv;
    __syncthreads();

    if (tid < OO) {
        float h = 0.f;
        #pragma unroll
        for (int tt = 0; tt < TT; ++tt) h += HpL[tt * OO + tid] * probsL[tt];
        HL[tid] = fmaxf(h, 0.f);
    }
    __syncthreads();

    if (tid < TT) {
        float acc = bout[tid];
        #pragma unroll
        for (int pp = 0; pp < OO; ++pp) acc += HL[pp] * Wout[tid * OO + pp];
        out[n * TT + tid] = acc;
    }
}

// ---------------------------------------------------------------------------
extern "C" void kernel_launch(void* const* d_in, const int* in_sizes, int n_in,
                              void* d_out, int out_size, void* d_ws, size_t ws_size,
                              hipStream_t stream)
{
    const float* x    = (const float*)d_in[0];
    const int*   ei   = (const int*)  d_in[1];
    const float* ew   = (const float*)d_in[2];
    const float* Wm   = (const float*)d_in[3];
    const float* Wz   = (const float*)d_in[4];
    const float* bz   = (const float*)d_in[5];
    // d_in[6] = Wr, d_in[7] = br  -> unused (reset gate multiplies H0 = 0)
    const float* Wh   = (const float*)d_in[8];
    const float* bh   = (const float*)d_in[9];
    const float* Lz   = (const float*)d_in[10];
    const float* blz  = (const float*)d_in[11];
    // d_in[12] = Lr, d_in[13] = blr -> unused
    const float* Lh   = (const float*)d_in[14];
    const float* blh  = (const float*)d_in[15];
    const float* att  = (const float*)d_in[16];
    const float* Wout = (const float*)d_in[17];
    const float* bout = (const float*)d_in[18];
    float* out = (float*)d_out;

    float* ws = (float*)d_ws;
    float* xf       = ws;                 // 19200
    float* norm     = ws + 19200;         // 1600
    float* normself = ws + 20800;         // 200
    float* probs    = ws + 21000;         // 12 (pad to 21024)
    float* xwz      = ws + 21024;         // 76800
    float* xwh      = ws + 97824;         // 76800

    gemv_kernel   <<<DD / 4, 256, 0, stream>>>(x, Wm, xf);
    xw_prep_kernel<<<NN + 1, 384, 0, stream>>>(xf, Wz, Wh, ei, ew, att,
                                               xwz, xwh, norm, normself, probs);
    final_kernel  <<<NN, 384, 0, stream>>>(ei, norm, normself, xwz, xwh,
                                           bz, bh, Lz, blz, Lh, blh,
                                           probs, Wout, bout, out);
}